// Round 3
// baseline (186.472 us; speedup 1.0000x reference)
//
#include <hip/hip_runtime.h>

#define DD 64

typedef float f4v __attribute__((ext_vector_type(4)));

// ---------------------------------------------------------------------------
// Pass 1: zero relevant / bitmap / count
__global__ void k_zero(int* __restrict__ relevant, unsigned* __restrict__ bitmap,
                       int* __restrict__ count, int N, int NB) {
    int i = blockIdx.x * blockDim.x + threadIdx.x;
    if (i == 0) *count = 0;
    if (i < N) relevant[i] = 0;
    if (i < NB) bitmap[i] = 0u;
}

// Pass 2: rel_ctx = mean over R rows (8 waves, coalesced); mark query nodes.
__global__ __launch_bounds__(512) void k_ctx(const float* __restrict__ rel, int R,
                                             const int* __restrict__ h_index, int B,
                                             float* __restrict__ ctx,
                                             int* __restrict__ relevant) {
    __shared__ float part[8][DD];
    int lane = threadIdx.x & 63;
    int w = threadIdx.x >> 6;
    float s0 = 0.f, s1 = 0.f;
    int r = w;
    for (; r + 16 <= R; r += 16) {
        s0 += rel[(size_t)r * DD + lane];
        s1 += rel[(size_t)(r + 8) * DD + lane];
    }
    for (; r < R; r += 8) s0 += rel[(size_t)r * DD + lane];
    part[w][lane] = s0 + s1;
    __syncthreads();
    int t = threadIdx.x;
    if (t < DD) {
        float tot = 0.f;
#pragma unroll
        for (int i = 0; i < 8; ++i) tot += part[i][t];
        ctx[t] = tot / (float)R;
    }
    if (t < B) relevant[h_index[t]] = 1;
}

// Pass 3: mark 1-hop neighbors of query nodes.
// Grid-stride, 16 edges/thread, 8 int4 loads in flight (MLP-deep).
__global__ __launch_bounds__(256) void k_mark(const int* __restrict__ src,
                                              const int* __restrict__ dst,
                                              const int* __restrict__ h_index, int B,
                                              int* __restrict__ relevant, int E) {
    __shared__ int hs[64];
    if (threadIdx.x < B) hs[threadIdx.x] = h_index[threadIdx.x];
    __syncthreads();
    const int nth = gridDim.x * blockDim.x;
    const int tid = blockIdx.x * blockDim.x + threadIdx.x;
    const int E16 = E & ~15;
    for (int base = tid * 16; base < E16; base += nth * 16) {
        int4 s[4], d[4];
#pragma unroll
        for (int u = 0; u < 4; ++u) s[u] = *(const int4*)(src + base + u * 4);
#pragma unroll
        for (int u = 0; u < 4; ++u) d[u] = *(const int4*)(dst + base + u * 4);
        for (int b = 0; b < B; ++b) {
            int h = hs[b];
#pragma unroll
            for (int u = 0; u < 4; ++u) {
                if (s[u].x == h) relevant[d[u].x] = 1;
                if (d[u].x == h) relevant[s[u].x] = 1;
                if (s[u].y == h) relevant[d[u].y] = 1;
                if (d[u].y == h) relevant[s[u].y] = 1;
                if (s[u].z == h) relevant[d[u].z] = 1;
                if (d[u].z == h) relevant[s[u].z] = 1;
                if (s[u].w == h) relevant[d[u].w] = 1;
                if (d[u].w == h) relevant[s[u].w] = 1;
            }
        }
    }
    for (int e = E16 + tid; e < E; e += nth) {
        int s = src[e], de = dst[e];
        for (int b = 0; b < B; ++b) {
            int h = hs[b];
            if (s == h) relevant[de] = 1;
            if (de == h) relevant[s] = 1;
        }
    }
}

// Pass 4: compact relevant node list; build bitmap; zero accumulators.
__global__ void k_compact(const int* __restrict__ relevant, int* __restrict__ rel_list,
                          int* __restrict__ count, unsigned* __restrict__ bitmap,
                          unsigned* __restrict__ cnt, unsigned* __restrict__ nbr,
                          float* __restrict__ feat, int N) {
    int n = blockIdx.x * blockDim.x + threadIdx.x;
    if (n >= N) return;
    if (relevant[n]) {
        int slot = atomicAdd(count, 1);
        rel_list[slot] = n;
        atomicOr(bitmap + (n >> 5), 1u << (n & 31));
        cnt[n] = 0u;
        nbr[n] = 0u;
        f4v z = (f4v)(0.f);
        f4v* f = (f4v*)(feat + (size_t)n * DD);
#pragma unroll
        for (int q = 0; q < DD / 4; ++q) f[q] = z;
    }
}

// Pass 5: edge accumulation; relevance via LDS bitmap; deep-MLP edge stream.
__device__ __forceinline__ void accum_edge(int s, int d, int e, unsigned rs, unsigned rd,
                                           const int* __restrict__ etype,
                                           const float* __restrict__ rel,
                                           float* __restrict__ feat,
                                           unsigned* __restrict__ cnt,
                                           unsigned* __restrict__ nbr) {
    if (!(rs | rd)) return;
    int w = (s != d) ? 1 : 0;
    int t = etype[e];                       // loaded only on the rare path
    const float* rrow = rel + (size_t)t * DD;
    float r[DD];
#pragma unroll
    for (int q = 0; q < DD / 4; ++q) {
        f4v v = *(const f4v*)(rrow + q * 4);
        r[q * 4 + 0] = v.x; r[q * 4 + 1] = v.y; r[q * 4 + 2] = v.z; r[q * 4 + 3] = v.w;
    }
    if (rs) {
        float* fs = feat + (size_t)s * DD;
#pragma unroll
        for (int q = 0; q < DD; ++q) atomicAdd(fs + q, r[q]);
        atomicAdd(cnt + s, 1u);
        if (w) atomicAdd(nbr + s, 1u);
    }
    if (rd && w) {
        float* fd = feat + (size_t)d * DD;
#pragma unroll
        for (int q = 0; q < DD; ++q) atomicAdd(fd + q, r[q]);
        atomicAdd(cnt + d, 1u);
        atomicAdd(nbr + d, 1u);
    }
}

__global__ __launch_bounds__(256) void k_accum(const int* __restrict__ src,
                                               const int* __restrict__ dst,
                                               const int* __restrict__ etype,
                                               const unsigned* __restrict__ bitmap, int NB,
                                               const float* __restrict__ rel,
                                               float* __restrict__ feat,
                                               unsigned* __restrict__ cnt,
                                               unsigned* __restrict__ nbr, int E) {
    extern __shared__ unsigned bm[];
    for (int i = threadIdx.x; i < NB; i += blockDim.x) bm[i] = bitmap[i];
    __syncthreads();
#define CHK(id) ((bm[(unsigned)(id) >> 5] >> ((unsigned)(id) & 31)) & 1u)
    const int nth = gridDim.x * blockDim.x;
    const int tid = blockIdx.x * blockDim.x + threadIdx.x;
    const int E16 = E & ~15;
    for (int base = tid * 16; base < E16; base += nth * 16) {
        int4 s[4], d[4];
#pragma unroll
        for (int u = 0; u < 4; ++u) s[u] = *(const int4*)(src + base + u * 4);
#pragma unroll
        for (int u = 0; u < 4; ++u) d[u] = *(const int4*)(dst + base + u * 4);
        unsigned m = 0u;
#pragma unroll
        for (int u = 0; u < 4; ++u) {
            m |= CHK(s[u].x) << (8 * u + 0);
            m |= CHK(d[u].x) << (8 * u + 1);
            m |= CHK(s[u].y) << (8 * u + 2);
            m |= CHK(d[u].y) << (8 * u + 3);
            m |= CHK(s[u].z) << (8 * u + 4);
            m |= CHK(d[u].z) << (8 * u + 5);
            m |= CHK(s[u].w) << (8 * u + 6);
            m |= CHK(d[u].w) << (8 * u + 7);
        }
        if (m == 0u) continue;
#pragma unroll
        for (int u = 0; u < 4; ++u) {
            accum_edge(s[u].x, d[u].x, base + u * 4 + 0, (m >> (8 * u + 0)) & 1u,
                       (m >> (8 * u + 1)) & 1u, etype, rel, feat, cnt, nbr);
            accum_edge(s[u].y, d[u].y, base + u * 4 + 1, (m >> (8 * u + 2)) & 1u,
                       (m >> (8 * u + 3)) & 1u, etype, rel, feat, cnt, nbr);
            accum_edge(s[u].z, d[u].z, base + u * 4 + 2, (m >> (8 * u + 4)) & 1u,
                       (m >> (8 * u + 5)) & 1u, etype, rel, feat, cnt, nbr);
            accum_edge(s[u].w, d[u].w, base + u * 4 + 3, (m >> (8 * u + 6)) & 1u,
                       (m >> (8 * u + 7)) & 1u, etype, rel, feat, cnt, nbr);
        }
    }
    for (int e = E16 + tid; e < E; e += nth) {
        int s = src[e], de = dst[e];
        unsigned rs = CHK(s), rd = CHK(de);
        accum_edge(s, de, e, rs, rd, etype, rel, feat, cnt, nbr);
    }
#undef CHK
}

// Pass 6: per relevant node: avg -> MLP -> final, written in place into feat.
__global__ __launch_bounds__(64) void k_mlp(
    const int* __restrict__ rel_list, const int* __restrict__ count,
    const unsigned* __restrict__ cnt, const unsigned* __restrict__ nbr,
    const float* __restrict__ ctx,
    const float* __restrict__ Wi1, const float* __restrict__ bi1,
    const float* __restrict__ Wi2, const float* __restrict__ bi2,
    const float* __restrict__ Wc1, const float* __restrict__ bc1,
    const float* __restrict__ Wc2, const float* __restrict__ bc2,
    const float* __restrict__ strength, float* __restrict__ feat) {
    int j = threadIdx.x;   // one wave per node
    int C = *count;
    float alpha = fminf(fmaxf(strength[0], 0.f), 0.3f);
    float ctxj = ctx[j];
    for (int i = blockIdx.x; i < C; i += gridDim.x) {
        int n = rel_list[i];
        float* frow = feat + (size_t)n * DD;
        unsigned c = cnt[n];
        if (c == 0u) { frow[j] = ctxj; continue; }
        float avg = frow[j] / (float)c;
        bool hasnbr = (nbr[n] > 0u);  // wave-uniform
        const float* W1 = hasnbr ? Wc1 : Wi1;
        const float* b1 = hasnbr ? bc1 : bi1;
        const float* W2 = hasnbr ? Wc2 : Wi2;
        const float* b2 = hasnbr ? bc2 : bi2;
        float h1 = b1[j];
#pragma unroll 4
        for (int k = 0; k < DD; ++k) {
            float a_k = __shfl(avg, k);
            float x2  = hasnbr ? a_k : __shfl(ctxj, k);
            h1 += a_k * W1[k * DD + j] + x2 * W1[(DD + k) * DD + j];
        }
        h1 = fmaxf(h1, 0.f);
        float out = b2[j];
#pragma unroll 4
        for (int k = 0; k < DD; ++k)
            out += __shfl(h1, k) * W2[k * DD + j];
        frow[j] = (1.f - alpha) * avg + alpha * out;
    }
}

// Pass 7: sparse writer — only relevant rows (rest zeroed by memset).
__global__ __launch_bounds__(64) void k_out_sparse(const int* __restrict__ rel_list,
                                                   const int* __restrict__ count,
                                                   const float* __restrict__ feat,
                                                   float* __restrict__ out, int N, int B) {
    int lane = threadIdx.x;
    int C = *count;
    size_t plane = (size_t)N * DD;
    for (int i = blockIdx.x; i < C; i += gridDim.x) {
        int n = rel_list[i];
        float v = feat[(size_t)n * DD + lane];
        float* p = out + (size_t)n * DD + lane;
        for (int b = 0; b < B; ++b) p[(size_t)b * plane] = v;
    }
}

extern "C" void kernel_launch(void* const* d_in, const int* in_sizes, int n_in,
                              void* d_out, int out_size, void* d_ws, size_t ws_size,
                              hipStream_t stream) {
    const int*   edge_index = (const int*)d_in[0];    // [2, E]
    const int*   edge_type  = (const int*)d_in[1];    // [E]
    const int*   h_index    = (const int*)d_in[2];    // [B]
    const float* rel_emb    = (const float*)d_in[3];  // [R, 64]
    const float* Wi1 = (const float*)d_in[5];
    const float* bi1 = (const float*)d_in[6];
    const float* Wi2 = (const float*)d_in[7];
    const float* bi2 = (const float*)d_in[8];
    const float* Wc1 = (const float*)d_in[9];
    const float* bc1 = (const float*)d_in[10];
    const float* Wc2 = (const float*)d_in[11];
    const float* bc2 = (const float*)d_in[12];
    const float* strength = (const float*)d_in[13];
    float* out = (float*)d_out;

    const int E = in_sizes[1];
    const int B = in_sizes[2];
    const int R = in_sizes[3] / DD;
    const int N = out_size / (B * DD);
    const int NB = (N + 31) / 32;
    const int* src = edge_index;
    const int* dst = edge_index + E;

    char* w = (char*)d_ws;
    size_t off = 0;
    auto carve = [&](size_t bytes) -> char* {
        char* p = w + off;
        off += (bytes + 255) & ~(size_t)255;
        return p;
    };
    float*    ctx      = (float*)carve(DD * sizeof(float));
    int*      count    = (int*)carve(sizeof(int));
    int*      relevant = (int*)carve((size_t)N * sizeof(int));
    unsigned* bitmap   = (unsigned*)carve((size_t)NB * sizeof(unsigned));
    unsigned* cnt      = (unsigned*)carve((size_t)N * sizeof(unsigned));
    unsigned* nbr      = (unsigned*)carve((size_t)N * sizeof(unsigned));
    int*      rel_list = (int*)carve((size_t)N * sizeof(int));
    float*    feat     = (float*)carve((size_t)N * DD * sizeof(float));
    (void)ws_size; (void)n_in;

    const int BLK = 256;
    int gN = (N + BLK - 1) / BLK;
    const int gE = 512;   // 512*256*16 >= 2M edges, deep-MLP streaming

    // Bulk-zero the 204.8 MB output at fill-engine rate; sparse rows written later.
    hipMemsetAsync(d_out, 0, (size_t)out_size * sizeof(float), stream);

    hipLaunchKernelGGL(k_zero, dim3(gN), dim3(BLK), 0, stream,
                       relevant, bitmap, count, N, NB);
    hipLaunchKernelGGL(k_ctx, dim3(1), dim3(512), 0, stream,
                       rel_emb, R, h_index, B, ctx, relevant);
    hipLaunchKernelGGL(k_mark, dim3(gE), dim3(BLK), 0, stream,
                       src, dst, h_index, B, relevant, E);
    hipLaunchKernelGGL(k_compact, dim3(gN), dim3(BLK), 0, stream,
                       relevant, rel_list, count, bitmap, cnt, nbr, feat, N);
    hipLaunchKernelGGL(k_accum, dim3(gE), dim3(BLK), (size_t)NB * sizeof(unsigned), stream,
                       src, dst, edge_type, bitmap, NB, rel_emb, feat, cnt, nbr, E);
    hipLaunchKernelGGL(k_mlp, dim3(512), dim3(64), 0, stream,
                       rel_list, count, cnt, nbr, ctx,
                       Wi1, bi1, Wi2, bi2, Wc1, bc1, Wc2, bc2, strength, feat);
    hipLaunchKernelGGL(k_out_sparse, dim3(512), dim3(64), 0, stream,
                       rel_list, count, feat, out, N, B);
}

// Round 5
// 104.526 us; speedup vs baseline: 1.7840x; 1.7840x over previous
//
#include <hip/hip_runtime.h>

#define DD 64

typedef float f4v __attribute__((ext_vector_type(4)));

// record: node (17b) | etype (9b) | w (1b)
#define PACK(n, t, w) ((((unsigned)(n)) << 10) | (((unsigned)(t)) << 1) | (unsigned)(w))

// ---------------------------------------------------------------------------
// Pass 1: zero bitmap + counters (counters[0]=node count, counters[1]=record count)
__global__ void k_zero(unsigned* __restrict__ bitmap, int NB, int* __restrict__ counters) {
    int i = blockIdx.x * blockDim.x + threadIdx.x;
    if (i < NB) bitmap[i] = 0u;
    if (i < 2) counters[i] = 0;
}

// Pass 2: rel_ctx = mean over R rows; mark query bits in bitmap.
__global__ __launch_bounds__(512) void k_ctx(const float* __restrict__ rel, int R,
                                             const int* __restrict__ h_index, int B,
                                             float* __restrict__ ctx,
                                             unsigned* __restrict__ bitmap) {
    __shared__ float part[8][DD];
    int lane = threadIdx.x & 63;
    int w = threadIdx.x >> 6;
    float s0 = 0.f, s1 = 0.f;
    int r = w;
    for (; r + 16 <= R; r += 16) {
        s0 += rel[(size_t)r * DD + lane];
        s1 += rel[(size_t)(r + 8) * DD + lane];
    }
    for (; r < R; r += 8) s0 += rel[(size_t)r * DD + lane];
    part[w][lane] = s0 + s1;
    __syncthreads();
    int t = threadIdx.x;
    if (t < DD) {
        float tot = 0.f;
#pragma unroll
        for (int i = 0; i < 8; ++i) tot += part[i][t];
        ctx[t] = tot / (float)R;
    }
    if (t < B) {
        int n = h_index[t];
        atomicOr(bitmap + ((unsigned)n >> 5), 1u << (n & 31));
    }
}

// Pass 3: mark 1-hop neighbors of query nodes (query ids uniform in registers).
__device__ __forceinline__ bool is_q(int v, const int* hq) {
    bool m = false;
#pragma unroll
    for (int b = 0; b < 8; ++b) m |= (v == hq[b]);
    return m;
}

__global__ __launch_bounds__(256) void k_mark(const int* __restrict__ src,
                                              const int* __restrict__ dst,
                                              const int* __restrict__ h_index, int B,
                                              unsigned* __restrict__ bitmap, int E) {
    int hq[8];
#pragma unroll
    for (int b = 0; b < 8; ++b) hq[b] = (b < B) ? h_index[b] : -1;
    const int nth = gridDim.x * blockDim.x;
    const int tid = blockIdx.x * blockDim.x + threadIdx.x;
    const int E16 = E & ~15;
#define MARK1(sv, dv)                                                        \
    do {                                                                     \
        if (is_q(sv, hq)) atomicOr(bitmap + ((unsigned)(dv) >> 5), 1u << ((dv) & 31)); \
        if (is_q(dv, hq)) atomicOr(bitmap + ((unsigned)(sv) >> 5), 1u << ((sv) & 31)); \
    } while (0)
    for (int base = tid * 16; base < E16; base += nth * 16) {
        int4 s[4], d[4];
#pragma unroll
        for (int u = 0; u < 4; ++u) s[u] = *(const int4*)(src + base + u * 4);
#pragma unroll
        for (int u = 0; u < 4; ++u) d[u] = *(const int4*)(dst + base + u * 4);
#pragma unroll
        for (int u = 0; u < 4; ++u) {
            MARK1(s[u].x, d[u].x);
            MARK1(s[u].y, d[u].y);
            MARK1(s[u].z, d[u].z);
            MARK1(s[u].w, d[u].w);
        }
    }
    for (int e = E16 + tid; e < E; e += nth) MARK1(src[e], dst[e]);
#undef MARK1
}

// Pass 4: compact bitmap -> rel_list (wave-aggregated counter; fully converged).
__global__ __launch_bounds__(256) void k_compact(const unsigned* __restrict__ bitmap, int NB,
                                                 int* __restrict__ rel_list,
                                                 int* __restrict__ counters) {
    int i = blockIdx.x * blockDim.x + threadIdx.x;
    int lane = threadIdx.x & 63;
    unsigned word = (i < NB) ? bitmap[i] : 0u;
    int c = __popc(word);
    int incl = c;
#pragma unroll
    for (int sh = 1; sh < 64; sh <<= 1) {
        int t = __shfl_up(incl, sh);
        if (lane >= sh) incl += t;
    }
    int total = __shfl(incl, 63);
    if (total == 0) return;
    int b0 = 0;
    if (lane == 0) b0 = atomicAdd(counters + 0, total);
    b0 = __shfl(b0, 0);
    int off = b0 + incl - c;
    while (word) {
        int bit = __ffs(word) - 1;
        word &= word - 1;
        rel_list[off++] = i * 32 + bit;
    }
}

// Pass 5: edge scan #2 -> packed incidence records.
// WAVE-CONVERGED chunk loop: chunk base is wave-uniform, per-lane `act`
// predicate guards loads; every lane participates in all shuffles/ballots.
__global__ __launch_bounds__(256) void k_scan(const int* __restrict__ src,
                                              const int* __restrict__ dst,
                                              const int* __restrict__ etype,
                                              const unsigned* __restrict__ bitmap, int NB,
                                              unsigned* __restrict__ rlist,
                                              int* __restrict__ counters, int E) {
    extern __shared__ unsigned bm[];
    for (int i = threadIdx.x; i < NB; i += blockDim.x) bm[i] = bitmap[i];
    __syncthreads();
#define CHK(id) ((bm[(unsigned)(id) >> 5] >> ((unsigned)(id) & 31)) & 1u)
    const int lane = threadIdx.x & 63;
    const int wid = (blockIdx.x * blockDim.x + threadIdx.x) >> 6;   // global wave id
    const int nw = (gridDim.x * blockDim.x) >> 6;
    const int E16 = E & ~15;
    const int CH = 64 * 16;                                          // edges per wave-chunk
    for (int cb = wid * CH; cb < E16; cb += nw * CH) {               // wave-uniform bound
        int base = cb + lane * 16;
        bool act = (base < E16);
        int4 s[4], d[4];
        if (act) {
#pragma unroll
            for (int u = 0; u < 4; ++u) s[u] = *(const int4*)(src + base + u * 4);
#pragma unroll
            for (int u = 0; u < 4; ++u) d[u] = *(const int4*)(dst + base + u * 4);
        }
        unsigned ms = 0u, md = 0u;   // per-edge s-record / d-record bits
        if (act) {
#define TST(sv, dv, idx)                                        \
            do {                                                \
                unsigned bs = CHK(sv), bd = CHK(dv);            \
                unsigned neq = ((sv) != (dv)) ? 1u : 0u;        \
                ms |= bs << (idx);                              \
                md |= (bd & neq) << (idx);                      \
            } while (0)
#pragma unroll
            for (int u = 0; u < 4; ++u) {
                TST(s[u].x, d[u].x, u * 4 + 0);
                TST(s[u].y, d[u].y, u * 4 + 1);
                TST(s[u].z, d[u].z, u * 4 + 2);
                TST(s[u].w, d[u].w, u * 4 + 3);
            }
#undef TST
        }
        int c = __popc(ms) + __popc(md);
        int incl = c;
#pragma unroll
        for (int sh = 1; sh < 64; sh <<= 1) {
            int t = __shfl_up(incl, sh);
            if (lane >= sh) incl += t;
        }
        int total = __shfl(incl, 63);
        if (total == 0) continue;                  // wave-uniform
        int b0 = 0;
        if (lane == 0) b0 = atomicAdd(counters + 1, total);
        b0 = __shfl(b0, 0);
        unsigned off = (unsigned)(b0 + incl - c);
        if (c) {
#define EMIT(sv, dv, idx)                                                     \
            do {                                                              \
                unsigned bit = 1u << (idx);                                   \
                if ((ms | md) & bit) {                                        \
                    int t = etype[base + (idx)];                              \
                    if (ms & bit) rlist[off++] = PACK(sv, t, ((sv) != (dv)) ? 1 : 0); \
                    if (md & bit) rlist[off++] = PACK(dv, t, 1);              \
                }                                                             \
            } while (0)
#pragma unroll
            for (int u = 0; u < 4; ++u) {
                EMIT(s[u].x, d[u].x, u * 4 + 0);
                EMIT(s[u].y, d[u].y, u * 4 + 1);
                EMIT(s[u].z, d[u].z, u * 4 + 2);
                EMIT(s[u].w, d[u].w, u * 4 + 3);
            }
#undef EMIT
        }
    }
    // tail (E not multiple of 16): per-thread, no cross-lane ops.
    const int tid = blockIdx.x * blockDim.x + threadIdx.x;
    const int nth = gridDim.x * blockDim.x;
    for (int e = E16 + tid; e < E; e += nth) {
        int sv = src[e], dv = dst[e];
        unsigned bs = CHK(sv), bd = CHK(dv);
        unsigned neq = (sv != dv) ? 1u : 0u;
        int k = (int)bs + (int)(bd & neq);
        if (k == 0) continue;
        int t = etype[e];
        int o = atomicAdd(counters + 1, k);
        if (bs) rlist[o++] = PACK(sv, t, neq);
        if (bd & neq) rlist[o] = PACK(dv, t, 1);
    }
#undef CHK
}

// Pass 6: per relevant node: gather from records (4 waves) + MLP + write B planes.
__device__ __forceinline__ void proc_rec(unsigned rv, bool valid, int n,
                                         const float* __restrict__ rel, int lane,
                                         float& fs, int& cnt, int& nb) {
    bool want = valid && ((int)(rv >> 10) == n);
    unsigned long long mk = __ballot(want);
    while (mk) {
        int l = __ffsll(mk) - 1;
        mk &= mk - 1;
        unsigned v = __shfl(rv, l);
        int t = (int)((v >> 1) & 0x1FFu);
        fs += rel[t * DD + lane];
        cnt += 1;
        nb += (int)(v & 1u);
    }
}

__global__ __launch_bounds__(256) void k_gather(
    const int* __restrict__ rel_list, const int* __restrict__ counters,
    const unsigned* __restrict__ rlist,
    const float* __restrict__ rel, const float* __restrict__ ctx,
    const float* __restrict__ Wi1, const float* __restrict__ bi1,
    const float* __restrict__ Wi2, const float* __restrict__ bi2,
    const float* __restrict__ Wc1, const float* __restrict__ bc1,
    const float* __restrict__ Wc2, const float* __restrict__ bc2,
    const float* __restrict__ strength, float* __restrict__ out, int N, int B) {
    __shared__ float part[4][DD];
    __shared__ int pc[4], pn[4];
    int lane = threadIdx.x & 63;
    int wv = threadIdx.x >> 6;
    int C = counters[0];
    int M = counters[1];
    float alpha = fminf(fmaxf(strength[0], 0.f), 0.3f);
    float ctxj = ctx[lane];
    int nchunk = (M + 255) / 256;
    size_t plane = (size_t)N * DD;
    for (int i = blockIdx.x; i < C; i += gridDim.x) {
        int n = rel_list[i];
        float fs = 0.f;
        int cnt = 0, nb = 0;
        for (int ch = wv; ch < nchunk; ch += 4) {
            int bbase = ch * 256 + lane * 4;
            uint4 r = *(const uint4*)(rlist + bbase);   // capacity-padded
            proc_rec(r.x, bbase + 0 < M, n, rel, lane, fs, cnt, nb);
            proc_rec(r.y, bbase + 1 < M, n, rel, lane, fs, cnt, nb);
            proc_rec(r.z, bbase + 2 < M, n, rel, lane, fs, cnt, nb);
            proc_rec(r.w, bbase + 3 < M, n, rel, lane, fs, cnt, nb);
        }
        part[wv][lane] = fs;
        if (lane == 0) { pc[wv] = cnt; pn[wv] = nb; }
        __syncthreads();
        if (wv == 0) {
            fs = part[0][lane] + part[1][lane] + part[2][lane] + part[3][lane];
            cnt = pc[0] + pc[1] + pc[2] + pc[3];
            nb = pn[0] + pn[1] + pn[2] + pn[3];
            float res;
            if (cnt == 0) {
                res = ctxj;                      // relevant, no edges -> rel_ctx
            } else {
                float avg = fs / (float)cnt;
                bool hasnbr = (nb > 0);          // wave-uniform
                const float* W1 = hasnbr ? Wc1 : Wi1;
                const float* b1 = hasnbr ? bc1 : bi1;
                const float* W2 = hasnbr ? Wc2 : Wi2;
                const float* b2 = hasnbr ? bc2 : bi2;
                float h1 = b1[lane];
#pragma unroll 4
                for (int k = 0; k < DD; ++k) {
                    float a_k = __shfl(avg, k);
                    float x2 = hasnbr ? a_k : __shfl(ctxj, k);
                    h1 += a_k * W1[k * DD + lane] + x2 * W1[(DD + k) * DD + lane];
                }
                h1 = fmaxf(h1, 0.f);
                float o = b2[lane];
#pragma unroll 4
                for (int k = 0; k < DD; ++k)
                    o += __shfl(h1, k) * W2[k * DD + lane];
                res = (1.f - alpha) * avg + alpha * o;
            }
            float* p = out + (size_t)n * DD + lane;
            for (int b = 0; b < B; ++b) p[(size_t)b * plane] = res;
        }
        __syncthreads();
    }
}

extern "C" void kernel_launch(void* const* d_in, const int* in_sizes, int n_in,
                              void* d_out, int out_size, void* d_ws, size_t ws_size,
                              hipStream_t stream) {
    const int*   edge_index = (const int*)d_in[0];    // [2, E]
    const int*   edge_type  = (const int*)d_in[1];    // [E]
    const int*   h_index    = (const int*)d_in[2];    // [B]
    const float* rel_emb    = (const float*)d_in[3];  // [R, 64]
    const float* Wi1 = (const float*)d_in[5];
    const float* bi1 = (const float*)d_in[6];
    const float* Wi2 = (const float*)d_in[7];
    const float* bi2 = (const float*)d_in[8];
    const float* Wc1 = (const float*)d_in[9];
    const float* bc1 = (const float*)d_in[10];
    const float* Wc2 = (const float*)d_in[11];
    const float* bc2 = (const float*)d_in[12];
    const float* strength = (const float*)d_in[13];
    float* out = (float*)d_out;

    const int E = in_sizes[1];
    const int B = in_sizes[2];
    const int R = in_sizes[3] / DD;
    const int N = out_size / (B * DD);
    const int NB = (N + 31) / 32;
    const int* src = edge_index;
    const int* dst = edge_index + E;

    char* w = (char*)d_ws;
    size_t off = 0;
    auto carve = [&](size_t bytes) -> char* {
        char* p = w + off;
        off += (bytes + 255) & ~(size_t)255;
        return p;
    };
    float*    ctx      = (float*)carve(DD * sizeof(float));
    int*      counters = (int*)carve(2 * sizeof(int));
    unsigned* bitmap   = (unsigned*)carve((size_t)NB * sizeof(unsigned));
    int*      rel_list = (int*)carve((size_t)N * sizeof(int));
    unsigned* rlist    = (unsigned*)carve(((size_t)2 * E + 512) * sizeof(unsigned));
    (void)ws_size; (void)n_in;

    const int BLK = 256;
    int gB = (NB + BLK - 1) / BLK;
    const int gE = 512;

    // Bulk-zero output at fill-engine rate; relevant rows overwritten by k_gather.
    hipMemsetAsync(d_out, 0, (size_t)out_size * sizeof(float), stream);

    hipLaunchKernelGGL(k_zero, dim3(gB), dim3(BLK), 0, stream, bitmap, NB, counters);
    hipLaunchKernelGGL(k_ctx, dim3(1), dim3(512), 0, stream,
                       rel_emb, R, h_index, B, ctx, bitmap);
    hipLaunchKernelGGL(k_mark, dim3(gE), dim3(BLK), 0, stream,
                       src, dst, h_index, B, bitmap, E);
    hipLaunchKernelGGL(k_compact, dim3(gB), dim3(BLK), 0, stream,
                       bitmap, NB, rel_list, counters);
    hipLaunchKernelGGL(k_scan, dim3(gE), dim3(BLK), (size_t)NB * sizeof(unsigned), stream,
                       src, dst, edge_type, bitmap, NB, rlist, counters, E);
    hipLaunchKernelGGL(k_gather, dim3(512), dim3(BLK), 0, stream,
                       rel_list, counters, rlist, rel_emb, ctx,
                       Wi1, bi1, Wi2, bi2, Wc1, bc1, Wc2, bc2, strength, out, N, B);
}